// Round 17
// baseline (168.376 us; speedup 1.0000x reference)
//
#include <hip/hip_runtime.h>
#include <hip/hip_bf16.h>
#include <stdint.h>

#define BATCH 2048
#define INF   512
#define OUTF  512
#define NB    60
#define KP    64      // padded per-j K: 60 basis + silu@60 + 3 zeros
#define LDK   128     // bytes per LDS row (64 bf16)
#define NJ    32      // j's per block (Ksplit = 16)

typedef float    f32x4 __attribute__((ext_vector_type(4)));
typedef unsigned u32x4 __attribute__((ext_vector_type(4)));

__device__ __forceinline__ unsigned short f2bf(float f) {
  unsigned u = __builtin_bit_cast(unsigned, f);
  u += 0x7fff + ((u >> 16) & 1);   // RNE
  return (unsigned short)(u >> 16);
}

__device__ __forceinline__ void gll16(const void* g, void* l) {
  __builtin_amdgcn_global_load_lds(
      (const __attribute__((address_space(1))) void*)g,
      (__attribute__((address_space(3))) void*)l, 16, 0, 0);
}

// Build the 16B A-fragment for k-slot q (k = 8q..8q+7) from the sparse rec:
// w0..w3 at k = s..s+3 (bit (s-8q)*16 of the 128-bit window), silu at k=60.
__device__ __forceinline__ u32x4 build_av(unsigned long long w, int s,
                                          unsigned silu, int q) {
  int rel = s - (q << 3);
  int sh  = rel << 4;
  unsigned long long lo = (rel >= 0) ? ((rel <= 3) ? (w << sh) : 0ull)
                                     : ((rel >= -3) ? (w >> (-sh)) : 0ull);
  unsigned long long hi = (rel >= 4) ? ((rel <= 7) ? (w << (sh - 64)) : 0ull)
                                     : ((rel >= 1) ? (w >> (64 - sh)) : 0ull);
  if (q == 7) hi |= (unsigned long long)silu;
  u32x4 av;
  av[0] = (unsigned)lo; av[1] = (unsigned)(lo >> 32);
  av[2] = (unsigned)hi; av[3] = (unsigned)(hi >> 32);
  return av;
}

// ---------------- prep_ct: CT[j][o][k] bf16 ----------------
__global__ __launch_bounds__(256) void prep_ct(const float* __restrict__ coeffs,
                                               const float* __restrict__ bw,
                                               unsigned short* __restrict__ CT) {
  int tg  = blockIdx.x * 256 + threadIdx.x;
  int row = tg >> 3;          // j*512 + o
  int pos = tg & 7;
  const float* src = coeffs + (long)row * NB;
  unsigned short v[8];
  if (pos < 7) {
    float4 c0 = *(const float4*)(src + pos * 8);
    float4 c1 = *(const float4*)(src + pos * 8 + 4);
    v[0]=f2bf(c0.x); v[1]=f2bf(c0.y); v[2]=f2bf(c0.z); v[3]=f2bf(c0.w);
    v[4]=f2bf(c1.x); v[5]=f2bf(c1.y); v[6]=f2bf(c1.z); v[7]=f2bf(c1.w);
  } else {
    float4 c0 = *(const float4*)(src + 56);
    v[0]=f2bf(c0.x); v[1]=f2bf(c0.y); v[2]=f2bf(c0.z); v[3]=f2bf(c0.w);
    v[4]=f2bf(bw[row]); v[5]=0; v[6]=0; v[7]=0;
  }
  uint4 pack;
  pack.x = (unsigned)v[0] | ((unsigned)v[1] << 16);
  pack.y = (unsigned)v[2] | ((unsigned)v[3] << 16);
  pack.z = (unsigned)v[4] | ((unsigned)v[5] << 16);
  pack.w = (unsigned)v[6] | ((unsigned)v[7] << 16);
  *(uint4*)(CT + (long)row * KP + pos * 8) = pack;
}

// ---------------- basis: records[j][b] ----------------
__global__ __launch_bounds__(256) void basis_kernel(const float* __restrict__ x,
                                                    const float* __restrict__ knots,
                                                    uint4* __restrict__ recs) {
  __shared__ float xl[64][65];
  __shared__ float Uk[64];
  int t  = threadIdx.x;
  int bt = blockIdx.x & 31, jt = blockIdx.x >> 5;
  int b0 = bt * 64, j0 = jt * 64;
  if (t < 64) Uk[t] = knots[t];
  for (int it = 0; it < 16; ++it) {
    int f = it * 256 + t;
    int r = f >> 6, c = f & 63;
    xl[r][c] = x[(long)(b0 + r) * INF + j0 + c];
  }
  __syncthreads();
  int bl = t & 63;
  int jg = t >> 6;
  for (int jj = 0; jj < 16; ++jj) {
    int jl = jg * 16 + jj;
    float xv = xl[bl][jl];
    int i = (int)floorf((xv + 1.0f) * 28.5f);
    i = max(0, min(56, i));
    if (xv < Uk[i + 3]) i--;
    else if (xv >= Uk[i + 4]) i++;
    i = max(0, min(56, i));
    int m = i + 3;
    float l1 = xv - Uk[m],     r1 = Uk[m + 1] - xv;
    float l2 = xv - Uk[m - 1], r2 = Uk[m + 2] - xv;
    float l3 = xv - Uk[m - 2], r3 = Uk[m + 3] - xv;
    float N0 = 1.0f, N1, N2, N3, temp, saved;
    temp = N0 / (r1 + l1); N0 = r1 * temp; N1 = l1 * temp;
    temp = N0 / (r1 + l2); N0 = r1 * temp; saved = l2 * temp;
    temp = N1 / (r2 + l1); N1 = saved + r2 * temp; N2 = l1 * temp;
    temp = N0 / (r1 + l3); N0 = r1 * temp; saved = l3 * temp;
    temp = N1 / (r2 + l2); N1 = saved + r2 * temp; saved = l2 * temp;
    temp = N2 / (r3 + l1); N2 = saved + r3 * temp; N3 = l1 * temp;
    float sil = xv / (1.0f + __expf(-xv));
    uint4 rec;
    rec.x = (unsigned)f2bf(N0) | ((unsigned)f2bf(N1) << 16);
    rec.y = (unsigned)f2bf(N2) | ((unsigned)f2bf(N3) << 16);
    rec.z = (unsigned)f2bf(sil) | ((unsigned)i << 16);
    rec.w = 0;
    recs[(long)(j0 + jl) * BATCH + b0 + bl] = rec;
  }
}

// ---------------- gemm: 128x128, reg-built A, LDS recl, depth-2 counted vmcnt ----------------
__global__ __launch_bounds__(256, 4) void gemm_kernel(const unsigned short* __restrict__ CT,
                                                      const uint4* __restrict__ recs,
                                                      float* __restrict__ out) {
  __shared__ __align__(16) unsigned short Bl[2][128 * KP];   // 2 x 16 KB
  __shared__ __align__(16) uint4 recl[2][128];               // 2 x 2 KB
  int t = threadIdx.x;
  int lane = t & 63, wid = t >> 6;
  int bx = blockIdx.x;
  int kt = bx & 15, mt = (bx >> 4) & 15, nt = bx >> 8;  // kt fastest: XCD j-slice affinity
  int b0 = mt * 128, o0 = nt * 128, j0 = kt * NJ;
  int wr = wid >> 1, wc = wid & 1;   // 2x2 waves, each 64x64
  int half = wid & 1;                // rec-stage half (waves 0/2 -> rows 0-63, 1/3 -> 64-127)

  f32x4 acc[4][4];
#pragma unroll
  for (int mm = 0; mm < 4; ++mm)
#pragma unroll
    for (int nn = 0; nn < 4; ++nn) { f32x4 z = {0.f, 0.f, 0.f, 0.f}; acc[mm][nn] = z; }

  // ---- issue set(J): 4 gll16 B-stage + 1 gll16 rec-stage = 5 vm ops, wave-uniform ----
  // (waves 0&2 / 1&3 write identical rec bytes to identical addresses: benign duplicate)
#define ISSUE(J, BUF)                                                            \
  {                                                                              \
    _Pragma("unroll")                                                            \
    for (int it = 0; it < 4; ++it) {                                             \
      int g = it * 256 + t, o = g >> 3, ls = g & 7, ks = ls ^ (o & 7);           \
      gll16(CT + ((long)((J) * 512 + o0 + o) << 6) + ks * 8,                     \
            (char*)Bl + (BUF) * 16384 + (it * 256 + wid * 64) * 16);             \
    }                                                                            \
    gll16(recs + ((long)(J) * BATCH + b0 + half * 64 + lane),                    \
          (char*)recl + (BUF) * 2048 + half * 64 * 16);                          \
  }

  // prologue: set(0) then set(1) (ordered sets)
  ISSUE(j0, 0)
  asm volatile("" ::: "memory");
  ISSUE(j0 + 1, 1)
  asm volatile("" ::: "memory");

#define BODY(CUR, JJ, VMSTR)                                                     \
  {                                                                              \
    asm volatile("s_waitcnt " VMSTR ::: "memory");  /* set(JJ) retired */        \
    __builtin_amdgcn_s_barrier();                   /* Bl/recl[CUR] ready */     \
    {                                                                            \
      const char*  B  = (const char*)Bl + (CUR) * 16384;                         \
      const uint4* RC = recl[CUR];                                               \
      unsigned long long w64[4]; int sS[4]; unsigned sil[4];                     \
      _Pragma("unroll")                                                          \
      for (int mm = 0; mm < 4; ++mm) {                                           \
        uint4 rc = RC[wr * 64 + mm * 16 + (lane & 15)];                          \
        w64[mm] = ((unsigned long long)rc.y << 32) | rc.x;                       \
        sS[mm]  = (int)(rc.z >> 16);                                             \
        sil[mm] = rc.z & 0xffffu;                                                \
      }                                                                          \
      _Pragma("unroll")                                                          \
      for (int kp = 0; kp < 2; ++kp) {                                           \
        int ksl = kp * 4 + (lane >> 4);                                          \
        u32x4 bv[4];                                                             \
        _Pragma("unroll")                                                        \
        for (int nn = 0; nn < 4; ++nn) {                                         \
          int col = wc * 64 + nn * 16 + (lane & 15);                             \
          bv[nn] = *(const u32x4*)(B + col * LDK + ((ksl ^ (col & 7)) << 4));    \
        }                                                                        \
        u32x4 av[4];                                                             \
        _Pragma("unroll")                                                        \
        for (int mm = 0; mm < 4; ++mm)                                           \
          av[mm] = build_av(w64[mm], sS[mm], sil[mm], ksl);                      \
        __builtin_amdgcn_s_setprio(1);                                          \
        _Pragma("unroll")                                                        \
        for (int mm = 0; mm < 4; ++mm)                                           \
          _Pragma("unroll")                                                      \
          for (int nn = 0; nn < 4; ++nn)                                         \
            asm volatile("v_mfma_f32_16x16x32_bf16 %0, %1, %2, %0"               \
                         : "+v"(acc[mm][nn]) : "v"(av[mm]), "v"(bv[nn]));        \
        __builtin_amdgcn_s_setprio(0);                                          \
      }                                                                          \
    }                                                                            \
    __builtin_amdgcn_s_barrier();   /* all reads of buf CUR done */              \
    if ((JJ) + 2 < NJ) {                                                         \
      ISSUE(j0 + (JJ) + 2, CUR)     /* refill freed buffer */                    \
      asm volatile("" ::: "memory");                                             \
    }                                                                            \
  }

  for (int jt = 0; jt < 15; ++jt) {
    BODY(0, 2 * jt,     "vmcnt(5)")
    BODY(1, 2 * jt + 1, "vmcnt(5)")
  }
  BODY(0, 30, "vmcnt(5)")
  BODY(1, 31, "vmcnt(0)")
#undef BODY
#undef ISSUE

  // epilogue: C/D layout col=lane&15, row=(lane>>4)*4+reg
  int r0 = (lane >> 4) * 4, c0 = lane & 15;
#pragma unroll
  for (int mm = 0; mm < 4; ++mm)
#pragma unroll
    for (int nn = 0; nn < 4; ++nn) {
      int grow = b0 + wr * 64 + mm * 16 + r0;
      int gcol = o0 + wc * 64 + nn * 16 + c0;
#pragma unroll
      for (int e = 0; e < 4; ++e)
        unsafeAtomicAdd(&out[(long)(grow + e) * OUTF + gcol], acc[mm][nn][e]);
    }
}

extern "C" void kernel_launch(void* const* d_in, const int* in_sizes, int n_in,
                              void* d_out, int out_size, void* d_ws, size_t ws_size,
                              hipStream_t stream) {
  const float* x      = (const float*)d_in[0];
  const float* coeffs = (const float*)d_in[1];
  const float* bw     = (const float*)d_in[2];
  const float* knots  = (const float*)d_in[3];
  float* out = (float*)d_out;

  const size_t CT_BYTES  = (size_t)INF * OUTF * KP * 2;   // 32 MB
  const size_t REC_BYTES = (size_t)INF * BATCH * 16;      // 16 MB
  if (ws_size < CT_BYTES + REC_BYTES) return;

  unsigned short* CT = (unsigned short*)d_ws;
  uint4* recs = (uint4*)((char*)d_ws + CT_BYTES);

  hipMemsetAsync(d_out, 0, (size_t)BATCH * OUTF * sizeof(float), stream);
  prep_ct<<<(INF * OUTF * 8) / 256, 256, 0, stream>>>(coeffs, bw, CT);
  basis_kernel<<<(BATCH / 64) * (INF / 64), 256, 0, stream>>>(x, knots, recs);
  gemm_kernel<<<1024, 256, 0, stream>>>(CT, recs, out);
}

// Round 18
// 151.355 us; speedup vs baseline: 1.1125x; 1.1125x over previous
//
#include <hip/hip_runtime.h>
#include <hip/hip_bf16.h>
#include <stdint.h>

#define BATCH 2048
#define INF   512
#define OUTF  512
#define NB    60
#define KP    64      // padded per-j K: 60 basis + silu@60 + 3 zeros
#define LDK   128     // bytes per LDS row (64 bf16)
#define NJ    64      // j's per block (Ksplit = 8)

typedef float    f32x4 __attribute__((ext_vector_type(4)));
typedef unsigned u32x4 __attribute__((ext_vector_type(4)));

struct rec3 { unsigned x, y, z; };

__device__ __forceinline__ unsigned short f2bf(float f) {
  unsigned u = __builtin_bit_cast(unsigned, f);
  u += 0x7fff + ((u >> 16) & 1);   // RNE
  return (unsigned short)(u >> 16);
}

__device__ __forceinline__ void gll16(const void* g, void* l) {
  __builtin_amdgcn_global_load_lds(
      (const __attribute__((address_space(1))) void*)g,
      (__attribute__((address_space(3))) void*)l, 16, 0, 0);
}

// Build the 16B A-fragment for k-slot q (k = 8q..8q+7) from the sparse rec:
// w0..w3 at k = s..s+3 (bit (s-8q)*16 of the 128-bit window), silu at k=60.
__device__ __forceinline__ u32x4 build_av(unsigned long long w, int s,
                                          unsigned silu, int q) {
  int rel = s - (q << 3);
  int sh  = rel << 4;
  unsigned long long lo = (rel >= 0) ? ((rel <= 3) ? (w << sh) : 0ull)
                                     : ((rel >= -3) ? (w >> (-sh)) : 0ull);
  unsigned long long hi = (rel >= 4) ? ((rel <= 7) ? (w << (sh - 64)) : 0ull)
                                     : ((rel >= 1) ? (w >> (64 - sh)) : 0ull);
  if (q == 7) hi |= (unsigned long long)silu;
  u32x4 av;
  av[0] = (unsigned)lo; av[1] = (unsigned)(lo >> 32);
  av[2] = (unsigned)hi; av[3] = (unsigned)(hi >> 32);
  return av;
}

// ---------------- prep_ct: CT[j][o][k] bf16 ----------------
__global__ __launch_bounds__(256) void prep_ct(const float* __restrict__ coeffs,
                                               const float* __restrict__ bw,
                                               unsigned short* __restrict__ CT) {
  int tg  = blockIdx.x * 256 + threadIdx.x;
  int row = tg >> 3;          // j*512 + o
  int pos = tg & 7;
  const float* src = coeffs + (long)row * NB;
  unsigned short v[8];
  if (pos < 7) {
    float4 c0 = *(const float4*)(src + pos * 8);
    float4 c1 = *(const float4*)(src + pos * 8 + 4);
    v[0]=f2bf(c0.x); v[1]=f2bf(c0.y); v[2]=f2bf(c0.z); v[3]=f2bf(c0.w);
    v[4]=f2bf(c1.x); v[5]=f2bf(c1.y); v[6]=f2bf(c1.z); v[7]=f2bf(c1.w);
  } else {
    float4 c0 = *(const float4*)(src + 56);
    v[0]=f2bf(c0.x); v[1]=f2bf(c0.y); v[2]=f2bf(c0.z); v[3]=f2bf(c0.w);
    v[4]=f2bf(bw[row]); v[5]=0; v[6]=0; v[7]=0;
  }
  uint4 pack;
  pack.x = (unsigned)v[0] | ((unsigned)v[1] << 16);
  pack.y = (unsigned)v[2] | ((unsigned)v[3] << 16);
  pack.z = (unsigned)v[4] | ((unsigned)v[5] << 16);
  pack.w = (unsigned)v[6] | ((unsigned)v[7] << 16);
  *(uint4*)(CT + (long)row * KP + pos * 8) = pack;
}

// ---------------- basis: records[j][b] ----------------
__global__ __launch_bounds__(256) void basis_kernel(const float* __restrict__ x,
                                                    const float* __restrict__ knots,
                                                    uint4* __restrict__ recs) {
  __shared__ float xl[64][65];
  __shared__ float Uk[64];
  int t  = threadIdx.x;
  int bt = blockIdx.x & 31, jt = blockIdx.x >> 5;
  int b0 = bt * 64, j0 = jt * 64;
  if (t < 64) Uk[t] = knots[t];
  for (int it = 0; it < 16; ++it) {
    int f = it * 256 + t;
    int r = f >> 6, c = f & 63;
    xl[r][c] = x[(long)(b0 + r) * INF + j0 + c];
  }
  __syncthreads();
  int bl = t & 63;
  int jg = t >> 6;
  for (int jj = 0; jj < 16; ++jj) {
    int jl = jg * 16 + jj;
    float xv = xl[bl][jl];
    int i = (int)floorf((xv + 1.0f) * 28.5f);
    i = max(0, min(56, i));
    if (xv < Uk[i + 3]) i--;
    else if (xv >= Uk[i + 4]) i++;
    i = max(0, min(56, i));
    int m = i + 3;
    float l1 = xv - Uk[m],     r1 = Uk[m + 1] - xv;
    float l2 = xv - Uk[m - 1], r2 = Uk[m + 2] - xv;
    float l3 = xv - Uk[m - 2], r3 = Uk[m + 3] - xv;
    float N0 = 1.0f, N1, N2, N3, temp, saved;
    temp = N0 / (r1 + l1); N0 = r1 * temp; N1 = l1 * temp;
    temp = N0 / (r1 + l2); N0 = r1 * temp; saved = l2 * temp;
    temp = N1 / (r2 + l1); N1 = saved + r2 * temp; N2 = l1 * temp;
    temp = N0 / (r1 + l3); N0 = r1 * temp; saved = l3 * temp;
    temp = N1 / (r2 + l2); N1 = saved + r2 * temp; saved = l2 * temp;
    temp = N2 / (r3 + l1); N2 = saved + r3 * temp; N3 = l1 * temp;
    float sil = xv / (1.0f + __expf(-xv));
    uint4 rec;
    rec.x = (unsigned)f2bf(N0) | ((unsigned)f2bf(N1) << 16);
    rec.y = (unsigned)f2bf(N2) | ((unsigned)f2bf(N3) << 16);
    rec.z = (unsigned)f2bf(sil) | ((unsigned)i << 16);
    rec.w = 0;
    recs[(long)(j0 + jl) * BATCH + b0 + bl] = rec;
  }
}

// ---------------- gemm: 128x128, reg-built A, depth-2 vmcnt(8), Ksplit=8 ----------------
__global__ __launch_bounds__(256, 2) void gemm_kernel(const unsigned short* __restrict__ CT,
                                                      const uint4* __restrict__ recs,
                                                      float* __restrict__ out) {
  __shared__ __align__(16) unsigned short Bl[2][128 * KP];   // 2 x 16 KB (only LDS)
  int t = threadIdx.x;
  int lane = t & 63, wid = t >> 6;
  int bx = blockIdx.x;
  int kt = bx & 7, mt = (bx >> 3) & 15, nt = bx >> 7;   // kt fastest: XCD j-slice affinity
  int b0 = mt * 128, o0 = nt * 128, j0 = kt * NJ;
  int wr = wid >> 1, wc = wid & 1;   // 2x2 waves, each 64x64
  int rrow = b0 + wr * 64 + (lane & 15);   // rec row base (mm adds 16)

  f32x4 acc[4][4];
#pragma unroll
  for (int mm = 0; mm < 4; ++mm)
#pragma unroll
    for (int nn = 0; nn < 4; ++nn) { f32x4 z = {0.f, 0.f, 0.f, 0.f}; acc[mm][nn] = z; }

  rec3 rc0[4], rc1[4];

  // ---- issue set(J): 4 rec reg-loads + 4 gll16 B-stage = 8 vm ops, wave-uniform ----
#define ISSUE(J, RC, BUF)                                                        \
  {                                                                              \
    const uint4* rbase = recs + (long)(J) * BATCH;                               \
    _Pragma("unroll")                                                            \
    for (int mm = 0; mm < 4; ++mm)                                               \
      RC[mm] = *(const rec3*)(rbase + rrow + mm * 16);                           \
    _Pragma("unroll")                                                            \
    for (int it = 0; it < 4; ++it) {                                             \
      int g = it * 256 + t, o = g >> 3, ls = g & 7, ks = ls ^ (o & 7);           \
      gll16(CT + ((long)((J) * 512 + o0 + o) << 6) + ks * 8,                     \
            (char*)Bl + (BUF) * 16384 + (it * 256 + wid * 64) * 16);             \
    }                                                                            \
  }

  // prologue: set(0) then set(1) (ordered sets)
  ISSUE(j0, rc0, 0)
  asm volatile("" ::: "memory");
  ISSUE(j0 + 1, rc1, 1)
  asm volatile("" ::: "memory");

#define BODY(CUR, JJ, RC, VMSTR)                                                 \
  {                                                                              \
    asm volatile("s_waitcnt " VMSTR ::: "memory");  /* set(JJ) retired */        \
    __builtin_amdgcn_s_barrier();                   /* Bl[CUR] ready */          \
    {                                                                            \
      const char* B = (const char*)Bl + (CUR) * 16384;                           \
      _Pragma("unroll")                                                          \
      for (int kp = 0; kp < 2; ++kp) {                                           \
        int ksl = kp * 4 + (lane >> 4);                                          \
        u32x4 bv[4];                                                             \
        _Pragma("unroll")                                                        \
        for (int nn = 0; nn < 4; ++nn) {                                         \
          int col = wc * 64 + nn * 16 + (lane & 15);                             \
          bv[nn] = *(const u32x4*)(B + col * LDK + ((ksl ^ (col & 7)) << 4));    \
        }                                                                        \
        u32x4 av[4];                                                             \
        _Pragma("unroll")                                                        \
        for (int mm = 0; mm < 4; ++mm) {                                         \
          unsigned long long w = ((unsigned long long)RC[mm].y << 32) | RC[mm].x;\
          av[mm] = build_av(w, (int)(RC[mm].z >> 16), RC[mm].z & 0xffffu, ksl);  \
        }                                                                        \
        __builtin_amdgcn_s_setprio(1);                                          \
        _Pragma("unroll")                                                        \
        for (int mm = 0; mm < 4; ++mm)                                           \
          _Pragma("unroll")                                                      \
          for (int nn = 0; nn < 4; ++nn)                                         \
            asm volatile("v_mfma_f32_16x16x32_bf16 %0, %1, %2, %0"               \
                         : "+v"(acc[mm][nn]) : "v"(av[mm]), "v"(bv[nn]));        \
        __builtin_amdgcn_s_setprio(0);                                          \
      }                                                                          \
    }                                                                            \
    __builtin_amdgcn_s_barrier();   /* all reads of Bl[CUR] done */              \
    if ((JJ) + 2 < NJ) {                                                         \
      ISSUE(j0 + (JJ) + 2, RC, CUR)  /* refill freed buffer + regs */            \
      asm volatile("" ::: "memory");                                             \
    }                                                                            \
  }

  for (int jt = 0; jt < 31; ++jt) {
    BODY(0, 2 * jt,     rc0, "vmcnt(8)")
    BODY(1, 2 * jt + 1, rc1, "vmcnt(8)")
  }
  BODY(0, 62, rc0, "vmcnt(8)")
  BODY(1, 63, rc1, "vmcnt(0)")
#undef BODY
#undef ISSUE

  // epilogue: C/D layout col=lane&15, row=(lane>>4)*4+reg
  int r0 = (lane >> 4) * 4, c0 = lane & 15;
#pragma unroll
  for (int mm = 0; mm < 4; ++mm)
#pragma unroll
    for (int nn = 0; nn < 4; ++nn) {
      int grow = b0 + wr * 64 + mm * 16 + r0;
      int gcol = o0 + wc * 64 + nn * 16 + c0;
#pragma unroll
      for (int e = 0; e < 4; ++e)
        unsafeAtomicAdd(&out[(long)(grow + e) * OUTF + gcol], acc[mm][nn][e]);
    }
}

extern "C" void kernel_launch(void* const* d_in, const int* in_sizes, int n_in,
                              void* d_out, int out_size, void* d_ws, size_t ws_size,
                              hipStream_t stream) {
  const float* x      = (const float*)d_in[0];
  const float* coeffs = (const float*)d_in[1];
  const float* bw     = (const float*)d_in[2];
  const float* knots  = (const float*)d_in[3];
  float* out = (float*)d_out;

  const size_t CT_BYTES  = (size_t)INF * OUTF * KP * 2;   // 32 MB
  const size_t REC_BYTES = (size_t)INF * BATCH * 16;      // 16 MB
  if (ws_size < CT_BYTES + REC_BYTES) return;

  unsigned short* CT = (unsigned short*)d_ws;
  uint4* recs = (uint4*)((char*)d_ws + CT_BYTES);

  hipMemsetAsync(d_out, 0, (size_t)BATCH * OUTF * sizeof(float), stream);
  prep_ct<<<(INF * OUTF * 8) / 256, 256, 0, stream>>>(coeffs, bw, CT);
  basis_kernel<<<(BATCH / 64) * (INF / 64), 256, 0, stream>>>(x, knots, recs);
  gemm_kernel<<<512, 256, 0, stream>>>(CT, recs, out);
}

// Round 20
// 107.502 us; speedup vs baseline: 1.5663x; 1.4079x over previous
//
#include <hip/hip_runtime.h>
#include <hip/hip_bf16.h>
#include <stdint.h>

#define BATCH 2048
#define INF   512
#define OUTF  512
#define NB    60
#define KP    64     // padded per-j K: 60 basis + silu@60 + 3 zeros
#define LDK   128    // bytes per LDS row (64 bf16)
#define NJ    64     // j's per block (Ksplit = 8)

typedef float    f32x4 __attribute__((ext_vector_type(4)));
typedef unsigned u32x4 __attribute__((ext_vector_type(4)));

__device__ __forceinline__ unsigned short f2bf(float f) {
  unsigned u = __builtin_bit_cast(unsigned, f);
  u += 0x7fff + ((u >> 16) & 1);   // RNE
  return (unsigned short)(u >> 16);
}

__device__ __forceinline__ void gll16(const void* g, void* l) {
  __builtin_amdgcn_global_load_lds(
      (const __attribute__((address_space(1))) void*)g,
      (__attribute__((address_space(3))) void*)l, 16, 0, 0);
}

// ---------------- fused prep: blocks [0,256) basis (FIRST - overlaps), [256,8448) CT ----------------
__global__ __launch_bounds__(256) void prep_fused(const float* __restrict__ coeffs,
                                                  const float* __restrict__ bw,
                                                  const float* __restrict__ x,
                                                  const float* __restrict__ knots,
                                                  unsigned short* __restrict__ CT,
                                                  uint4* __restrict__ recs) {
  __shared__ float xl[64][65];
  __shared__ float Uk[64];
  if (blockIdx.x >= 256) {
    // ---- CT path ----
    int tg  = (blockIdx.x - 256) * 256 + threadIdx.x;
    int row = tg >> 3;          // j*512 + o
    int pos = tg & 7;
    const float* src = coeffs + (long)row * NB;
    unsigned short v[8];
    if (pos < 7) {
      float4 c0 = *(const float4*)(src + pos * 8);
      float4 c1 = *(const float4*)(src + pos * 8 + 4);
      v[0]=f2bf(c0.x); v[1]=f2bf(c0.y); v[2]=f2bf(c0.z); v[3]=f2bf(c0.w);
      v[4]=f2bf(c1.x); v[5]=f2bf(c1.y); v[6]=f2bf(c1.z); v[7]=f2bf(c1.w);
    } else {
      float4 c0 = *(const float4*)(src + 56);
      v[0]=f2bf(c0.x); v[1]=f2bf(c0.y); v[2]=f2bf(c0.z); v[3]=f2bf(c0.w);
      v[4]=f2bf(bw[row]); v[5]=0; v[6]=0; v[7]=0;
    }
    uint4 pack;
    pack.x = (unsigned)v[0] | ((unsigned)v[1] << 16);
    pack.y = (unsigned)v[2] | ((unsigned)v[3] << 16);
    pack.z = (unsigned)v[4] | ((unsigned)v[5] << 16);
    pack.w = (unsigned)v[6] | ((unsigned)v[7] << 16);
    *(uint4*)(CT + (long)row * KP + pos * 8) = pack;
    return;
  }
  // ---- basis path (blocks 0..255, scheduled first -> overlaps CT blocks) ----
  int bid = blockIdx.x;
  int t  = threadIdx.x;
  int bt = bid & 31, jt = bid >> 5;
  int b0 = bt * 64, j0 = jt * 64;
  if (t < 64) Uk[t] = knots[t];
  for (int it = 0; it < 16; ++it) {
    int f = it * 256 + t;
    int r = f >> 6, c = f & 63;
    xl[r][c] = x[(long)(b0 + r) * INF + j0 + c];
  }
  __syncthreads();
  int bl = t & 63;
  int jg = t >> 6;
  for (int jj = 0; jj < 16; ++jj) {
    int jl = jg * 16 + jj;
    float xv = xl[bl][jl];
    int i = (int)floorf((xv + 1.0f) * 28.5f);
    i = max(0, min(56, i));
    if (xv < Uk[i + 3]) i--;
    else if (xv >= Uk[i + 4]) i++;
    i = max(0, min(56, i));
    int m = i + 3;
    float l1 = xv - Uk[m],     r1 = Uk[m + 1] - xv;
    float l2 = xv - Uk[m - 1], r2 = Uk[m + 2] - xv;
    float l3 = xv - Uk[m - 2], r3 = Uk[m + 3] - xv;
    float N0 = 1.0f, N1, N2, N3, temp, saved;
    temp = N0 / (r1 + l1); N0 = r1 * temp; N1 = l1 * temp;
    temp = N0 / (r1 + l2); N0 = r1 * temp; saved = l2 * temp;
    temp = N1 / (r2 + l1); N1 = saved + r2 * temp; N2 = l1 * temp;
    temp = N0 / (r1 + l3); N0 = r1 * temp; saved = l3 * temp;
    temp = N1 / (r2 + l2); N1 = saved + r2 * temp; saved = l2 * temp;
    temp = N2 / (r3 + l1); N2 = saved + r3 * temp; N3 = l1 * temp;
    float sil = xv / (1.0f + __expf(-xv));
    uint4 rec;
    rec.x = (unsigned)f2bf(N0) | ((unsigned)f2bf(N1) << 16);
    rec.y = (unsigned)f2bf(N2) | ((unsigned)f2bf(N3) << 16);
    rec.z = (unsigned)f2bf(sil) | ((unsigned)i << 16);
    rec.w = 0;
    recs[(long)(j0 + jl) * BATCH + b0 + bl] = rec;
  }
}

// ---------------- gemm: R10-exact — 128x128, dbuf, counted vmcnt(5), Ksplit=8 ----------------
__global__ __launch_bounds__(256, 2) void gemm_kernel(const unsigned short* __restrict__ CT,
                                                      const uint4* __restrict__ recs,
                                                      float* __restrict__ out) {
  __shared__ __align__(16) unsigned short Bl[2][128 * KP];   // 2 x 16 KB
  __shared__ __align__(16) unsigned short Al[2][128 * KP];   // 2 x 16 KB
  int t = threadIdx.x;
  int lane = t & 63, wid = t >> 6;
  int bx = blockIdx.x;
  // XCD-aware: kt fastest -> all blocks sharing a CT j-slice land on one XCD
  int kt = bx & 7, mt = (bx >> 3) & 15, nt = bx >> 7;
  int b0 = mt * 128, o0 = nt * 128, j0 = kt * 64;
  int wr = wid >> 1, wc = wid & 1;   // 2x2 waves, 64x64 each
  int r  = t & 127;                  // scatter row
  int eh = t >> 7;                   // 0: e=0,1 ; 1: e=2,3 + silu

  f32x4 acc[4][4];
#pragma unroll
  for (int mm = 0; mm < 4; ++mm)
#pragma unroll
    for (int nn = 0; nn < 4; ++nn) { f32x4 z = {0.f, 0.f, 0.f, 0.f}; acc[mm][nn] = z; }

  // zero both A buffers once (32 KB)
#pragma unroll
  for (int it = 0; it < 8; ++it)
    ((uint4*)Al)[it * 256 + t] = make_uint4(0, 0, 0, 0);

  // prologue: stage buf0 for j0, load rec for jj=0
#pragma unroll
  for (int it = 0; it < 4; ++it) {
    int g = it * 256 + t, o = g >> 3, ls = g & 7, ks = ls ^ (o & 7);
    gll16(CT + ((long)(j0 * 512 + o0 + o) << 6) + ks * 8,
          (char*)Bl + (it * 256 + wid * 64) * 16);
  }
  uint4 recA = recs[(long)j0 * BATCH + b0 + r];
  uint4 recB;
  int olds0 = 0, olds1 = 0;
  asm volatile("s_waitcnt lgkmcnt(0)" ::: "memory");   // zero-writes retired

  // Race-free scatter invariant: stale slots inside the NEW span are skipped
#define CLR(K)                                                                   \
  if ((K) < s || (K) > s + 3)                                                    \
    *(unsigned short*)(A + r * LDK + ((((K) >> 3) ^ (r & 7)) << 4) + ((K) & 7) * 2) = 0;
#define PUT(K, V)                                                                \
  *(unsigned short*)(A + r * LDK + ((((K) >> 3) ^ (r & 7)) << 4) + ((K) & 7) * 2) = (unsigned short)(V);

#define BODY(CUR, JJ, RECUSE, RECLOAD, OLDS)                                     \
  {                                                                              \
    if ((JJ) + 1 < NJ) {                                                         \
      int jn = j0 + (JJ) + 1;                                                    \
      _Pragma("unroll")                                                          \
      for (int it = 0; it < 4; ++it) {                                           \
        int g = it * 256 + t, o = g >> 3, ls = g & 7, ks = ls ^ (o & 7);         \
        gll16(CT + ((long)(jn * 512 + o0 + o) << 6) + ks * 8,                    \
              (char*)Bl + (1 - (CUR)) * 16384 + (it * 256 + wid * 64) * 16);     \
      }                                                                          \
      RECLOAD = recs[(long)jn * BATCH + b0 + r];                                 \
      asm volatile("s_waitcnt vmcnt(5)" ::: "memory");                           \
    } else {                                                                     \
      asm volatile("s_waitcnt vmcnt(0)" ::: "memory");                           \
    }                                                                            \
    __builtin_amdgcn_s_barrier();       /* Bl[CUR] + A-zero-state visible */     \
    {                                                                            \
      char* A = (char*)Al + (CUR) * 16384;                                       \
      int s = (int)(RECUSE.z >> 16);                                             \
      if (eh == 0) {                                                             \
        int k0 = OLDS, k1 = OLDS + 1;                                            \
        CLR(k0) CLR(k1)                                                          \
        PUT(s,     RECUSE.x)                                                     \
        PUT(s + 1, RECUSE.x >> 16)                                               \
      } else {                                                                   \
        int k0 = OLDS + 2, k1 = OLDS + 3;                                        \
        CLR(k0) CLR(k1)                                                          \
        PUT(s + 2, RECUSE.y)                                                     \
        PUT(s + 3, RECUSE.y >> 16)                                               \
        *(unsigned short*)(A + r * LDK + ((7 ^ (r & 7)) << 4) + 8) = (unsigned short)RECUSE.z; \
      }                                                                          \
      OLDS = s;                                                                  \
    }                                                                            \
    asm volatile("s_waitcnt lgkmcnt(0)" ::: "memory");                           \
    __builtin_amdgcn_s_barrier();       /* scatter visible */                    \
    {                                                                            \
      const char* A = (const char*)Al + (CUR) * 16384;                           \
      const char* B = (const char*)Bl + (CUR) * 16384;                           \
      _Pragma("unroll")                                                          \
      for (int kp = 0; kp < 2; ++kp) {                                           \
        int ksl = kp * 4 + (lane >> 4);                                          \
        u32x4 av[4], bv[4];                                                      \
        _Pragma("unroll")                                                        \
        for (int mm = 0; mm < 4; ++mm) {                                         \
          int row = wr * 64 + mm * 16 + (lane & 15);                             \
          av[mm] = *(const u32x4*)(A + row * LDK + ((ksl ^ (row & 7)) << 4));    \
        }                                                                        \
        _Pragma("unroll")                                                        \
        for (int nn = 0; nn < 4; ++nn) {                                         \
          int col = wc * 64 + nn * 16 + (lane & 15);                             \
          bv[nn] = *(const u32x4*)(B + col * LDK + ((ksl ^ (col & 7)) << 4));    \
        }                                                                        \
        _Pragma("unroll")                                                        \
        for (int mm = 0; mm < 4; ++mm)                                           \
          _Pragma("unroll")                                                      \
          for (int nn = 0; nn < 4; ++nn)                                         \
            asm volatile("v_mfma_f32_16x16x32_bf16 %0, %1, %2, %0"               \
                         : "+v"(acc[mm][nn]) : "v"(av[mm]), "v"(bv[nn]));        \
      }                                                                          \
    }                                                                            \
    asm volatile("s_waitcnt lgkmcnt(0)" ::: "memory");                           \
    __builtin_amdgcn_s_barrier();       /* reads done before next restage */     \
  }

  for (int jt = 0; jt < 32; ++jt) {
    BODY(0, 2 * jt,     recA, recB, olds0)
    BODY(1, 2 * jt + 1, recB, recA, olds1)
  }
#undef BODY
#undef CLR
#undef PUT

  // epilogue: C/D layout col=lane&15, row=(lane>>4)*4+reg
  int r0 = (lane >> 4) * 4, c0 = lane & 15;
#pragma unroll
  for (int mm = 0; mm < 4; ++mm)
#pragma unroll
    for (int nn = 0; nn < 4; ++nn) {
      int grow = b0 + wr * 64 + mm * 16 + r0;
      int gcol = o0 + wc * 64 + nn * 16 + c0;
#pragma unroll
      for (int e = 0; e < 4; ++e)
        unsafeAtomicAdd(&out[(long)(grow + e) * OUTF + gcol], acc[mm][nn][e]);
    }
}

extern "C" void kernel_launch(void* const* d_in, const int* in_sizes, int n_in,
                              void* d_out, int out_size, void* d_ws, size_t ws_size,
                              hipStream_t stream) {
  const float* x      = (const float*)d_in[0];
  const float* coeffs = (const float*)d_in[1];
  const float* bw     = (const float*)d_in[2];
  const float* knots  = (const float*)d_in[3];
  float* out = (float*)d_out;

  const size_t CT_BYTES  = (size_t)INF * OUTF * KP * 2;   // 32 MB
  const size_t REC_BYTES = (size_t)INF * BATCH * 16;      // 16 MB
  if (ws_size < CT_BYTES + REC_BYTES) return;

  unsigned short* CT = (unsigned short*)d_ws;
  uint4* recs = (uint4*)((char*)d_ws + CT_BYTES);

  hipMemsetAsync(d_out, 0, (size_t)BATCH * OUTF * sizeof(float), stream);
  prep_fused<<<256 + 8192, 256, 0, stream>>>(coeffs, bw, x, knots, CT, recs);
  gemm_kernel<<<512, 256, 0, stream>>>(CT, recs, out);
}